// Round 11
// baseline (132.819 us; speedup 1.0000x reference)
//
#include <hip/hip_runtime.h>
#include <math.h>

namespace {
constexpr int Bc = 4, Sc = 4096, Dc = 768, Gc = 64, Wc = 16, Rc = 4;
constexpr int NWc = Sc / Wc;          // 256 windows per batch row
constexpr int KEEPc = Wc - Rc;        // 12 kept tokens per window
constexpr int Ec = Wc - 1;            // 15 adjacent edges
constexpr int NQc = Dc / 4;           // 192 float4 per x row
constexpr int SQ4 = Sc / 4;           // 1024 float4 per s row
constexpr size_t X_ELEMS = (size_t)Bc * NWc * KEEPc * Dc;
constexpr size_t S_ELEMS = (size_t)Bc * NWc * KEEPc * Sc;

typedef float vf4 __attribute__((ext_vector_type(4)));
typedef float f32x4 __attribute__((ext_vector_type(4)));
typedef short bf16x8 __attribute__((ext_vector_type(8)));

__device__ inline short f2bf(float f) {      // native HW cvt, compiler packs pairs
  return __builtin_bit_cast(short, (__bf16)f);
}
}

// One block per window, 512 threads (8 waves), 4 KB LDS -> 4 blocks/CU.
// Phase 1 (waves 0-3): g = xw@Wg via MFMA, A direct from global (L2), -> gl.
// One barrier. All waves: redundant reduce + greedy select, pack row map in regs.
// Phase 2 (all waves): stream 12 s-rows as wave-chunks (4-deep, NT stores),
// then x_out (global reads, L2-hot) + p_out.
__global__ __launch_bounds__(512)
void tm_fused(const float* __restrict__ x, const float* __restrict__ src,
              const int* __restrict__ pos, const float* __restrict__ Wg,
              float* __restrict__ out) {
  const int wid = blockIdx.x;          // 0..1023
  const int b = wid >> 8;
  const int n = wid & (NWc - 1);
  const int tid = threadIdx.x;
  const int lane = tid & 63;
  const int wv = tid >> 6;             // 0..7

  __shared__ float gl[Wc][Gc];         // 4 KB: g = x @ Wg

  const size_t winTok = (size_t)(b * Sc + n * Wc);
  const float4* xg = reinterpret_cast<const float4*>(x + winTok * Dc);

  // ---- phase 1: MFMA gating GEMM (waves 0-3), A straight from global ----
  if (wv < 4) {
    const int arow = lane & 15;
    const int kg = lane >> 4;
    const int col = 16 * wv + arow;
    f32x4 cacc = {0.f, 0.f, 0.f, 0.f};
    for (int s = 0; s < 24; ++s) {
      const float4 a0 = xg[arow * NQc + s * 8 + kg * 2];
      const float4 a1 = xg[arow * NQc + s * 8 + kg * 2 + 1];
      bf16x8 af;
      af[0] = f2bf(a0.x); af[1] = f2bf(a0.y); af[2] = f2bf(a0.z); af[3] = f2bf(a0.w);
      af[4] = f2bf(a1.x); af[5] = f2bf(a1.y); af[6] = f2bf(a1.z); af[7] = f2bf(a1.w);
      const int kbase = s * 32 + kg * 8;
      bf16x8 bf;
#pragma unroll
      for (int j = 0; j < 8; ++j) bf[j] = f2bf(Wg[(size_t)(kbase + j) * Gc + col]);
      cacc = __builtin_amdgcn_mfma_f32_16x16x32_bf16(af, bf, cacc, 0, 0, 0);
    }
#pragma unroll
    for (int r = 0; r < 4; ++r) gl[kg * 4 + r][col] = cacc[r];
  }
  __syncthreads();

  // ---- reduce norms^2 + adjacent dots; greedy select (redundant per wave) ----
  float red[Wc + Ec];
  {
    float g[Wc];
#pragma unroll
    for (int w = 0; w < Wc; ++w) g[w] = gl[w][lane];
#pragma unroll
    for (int w = 0; w < Wc; ++w) red[w] = g[w] * g[w];
#pragma unroll
    for (int e = 0; e < Ec; ++e) red[Wc + e] = g[e] * g[e + 1];
  }
#pragma unroll
  for (int m = 1; m < 64; m <<= 1) {
#pragma unroll
    for (int i = 0; i < Wc + Ec; ++i) red[i] += __shfl_xor(red[i], m, 64);
  }

  float nr[Wc];
#pragma unroll
  for (int w = 0; w < Wc; ++w) nr[w] = sqrtf(red[w]);

  float sv[Ec];
#pragma unroll
  for (int e = 0; e < Ec; ++e)
    sv[e] = red[Wc + e] / (fmaxf(nr[e], 1e-12f) * fmaxf(nr[e + 1], 1e-12f));

  unsigned sel = 0, used = 0;
#pragma unroll
  for (int r = 0; r < Rc; ++r) {
    float best = -1e30f;
    int bi = 0;
#pragma unroll
    for (int e = 0; e < Ec; ++e) {
      const bool ok = ((used >> e) & 3u) == 0u;
      const float v = ok ? sv[e] : -1e30f;
      if (v > best) { best = v; bi = e; }   // strict > => smallest index wins ties
    }
    sel |= (1u << bi);
    used |= (3u << bi);
  }

  // pack kept-row map: wmap[4k+3:4k] = source token of kept row k; mgb bit k
  unsigned long long wmap = 0ull;
  unsigned mgb = 0;
  {
    int c = 0;
#pragma unroll
    for (int t = 0; t < Wc; ++t) {
      const bool kept = (t == 0) || (((sel >> (t - 1)) & 1u) == 0u);
      if (kept) {
        wmap |= (unsigned long long)t << (4 * c);
        if (t < Ec && ((sel >> t) & 1u)) mgb |= 1u << c;
        ++c;
      }
    }
  }

  // ---- phase 2a: s-rows as 192 wave-chunks (64 f4 each), 4-deep batches ----
  const vf4* src4 = reinterpret_cast<const vf4*>(src);
  vf4* outS4 = reinterpret_cast<vf4*>(out + X_ELEMS);
#pragma unroll 1
  for (int j = 0; j < 24; j += 4) {
    vf4 v[4];
    int kk[4], part[4];
#pragma unroll
    for (int jj = 0; jj < 4; ++jj) {
      const int ch = wv + 8 * (j + jj);          // wave-uniform chunk id
      kk[jj] = ch >> 4;
      part[jj] = ch & 15;
      const int wrow = (int)((wmap >> (4 * kk[jj])) & 15ull);
      v[jj] = src4[(winTok + wrow) * SQ4 + part[jj] * 64 + lane];
    }
#pragma unroll
    for (int jj = 0; jj < 4; ++jj) {
      if ((mgb >> kk[jj]) & 1u) {                // wave-uniform branch
        const int wrow = (int)((wmap >> (4 * kk[jj])) & 15ull);
        v[jj] = v[jj] + src4[(winTok + wrow + 1) * SQ4 + part[jj] * 64 + lane];
      }
    }
#pragma unroll
    for (int jj = 0; jj < 4; ++jj) {
      __builtin_nontemporal_store(
          v[jj], outS4 + ((size_t)wid * KEEPc + kk[jj]) * SQ4 + part[jj] * 64 + lane);
    }
  }

  // ---- phase 2b: x_out rows (wave w -> row w; waves 0-3 also rows 8-11) ----
  const vf4* xg4 = reinterpret_cast<const vf4*>(x + winTok * Dc);
#pragma unroll 1
  for (int k = wv; k < KEEPc; k += 8) {
    const int w = (int)((wmap >> (4 * k)) & 15ull);
    const bool mg = ((mgb >> k) & 1u) != 0;
    float aS = 1.f, bS = 0.f;
    if (mg) {
      float wi_ = 0.f, wj_ = 0.f;
#pragma unroll
      for (int t2 = 0; t2 < Wc; ++t2) {
        wi_ = (t2 == w) ? nr[t2] : wi_;
        wj_ = (t2 == w + 1) ? nr[t2] : wj_;
      }
      const float tot = wi_ + wj_ + 1e-8f;
      aS = wi_ / tot;
      bS = wj_ / tot;
    }
    const vf4* r1 = xg4 + (size_t)w * NQc;
    const vf4* r2 = xg4 + (size_t)(mg ? (w + 1) : w) * NQc;
    vf4* o = reinterpret_cast<vf4*>(out + (size_t)(wid * KEEPc + k) * Dc);
#pragma unroll
    for (int it = 0; it < 3; ++it) {
      const int i = lane + 64 * it;
      const vf4 a = r1[i];
      const vf4 bb = r2[i];
      __builtin_nontemporal_store(aS * a + bS * bb, o + i);
    }
  }

  // ---- p_out ----
  if (wv == 0 && lane < KEEPc) {
    const int w = (int)((wmap >> (4 * lane)) & 15ull);
    out[X_ELEMS + S_ELEMS + (size_t)(wid * KEEPc + lane)] =
        (float)pos[winTok + w];
  }
}

extern "C" void kernel_launch(void* const* d_in, const int* in_sizes, int n_in,
                              void* d_out, int out_size, void* d_ws, size_t ws_size,
                              hipStream_t stream) {
  const float* x = (const float*)d_in[0];
  const float* src = (const float*)d_in[1];
  const int* pos = (const int*)d_in[2];
  const float* Wg = (const float*)d_in[3];
  float* out = (float*)d_out;

  tm_fused<<<dim3(Bc * NWc), dim3(512), 0, stream>>>(x, src, pos, Wg, out);
}

// Round 12
// 132.055 us; speedup vs baseline: 1.0058x; 1.0058x over previous
//
#include <hip/hip_runtime.h>
#include <math.h>

namespace {
constexpr int Bc = 4, Sc = 4096, Dc = 768, Gc = 64, Wc = 16, Rc = 4;
constexpr int NWc = Sc / Wc;          // 256 windows per batch row
constexpr int KEEPc = Wc - Rc;        // 12 kept tokens per window
constexpr int Ec = Wc - 1;            // 15 adjacent edges
constexpr int NQc = Dc / 4;           // 192 float4 per x row
constexpr int PQ = NQc + 1;           // padded LDS row stride (f4)
constexpr size_t X_ELEMS = (size_t)Bc * NWc * KEEPc * Dc;
constexpr size_t S_ELEMS = (size_t)Bc * NWc * KEEPc * Sc;
constexpr int NROWS = Bc * NWc * KEEPc;                    // 12288 output rows

typedef float vf4 __attribute__((ext_vector_type(4)));
typedef float f32x4 __attribute__((ext_vector_type(4)));
typedef short bf16x8 __attribute__((ext_vector_type(8)));

__device__ inline short f2bf(float f) {      // native HW cvt, compiler packs pairs
  return __builtin_bit_cast(short, (__bf16)f);
}
}

// ---- K1: MFMA gating GEMM + greedy selection + x_out + p_out + meta ----
// (round-9 winner, unchanged: ~15-18 us, near its 88 MB memory floor)
__global__ __launch_bounds__(256)
void tm_select(const float* __restrict__ x, const int* __restrict__ pos,
               const float* __restrict__ Wg, float* __restrict__ out,
               int* __restrict__ meta) {
  const int wid = blockIdx.x;          // 0..1023
  const int b = wid >> 8;
  const int n = wid & (NWc - 1);
  const int tid = threadIdx.x;
  const int lane = tid & 63;
  const int wq = tid >> 6;

  __shared__ float4 xs4[Wc * PQ];      // ~49 KB, padded rows
  __shared__ float gl[Wc][Gc];         // 4 KB: g = x @ Wg

  const size_t winTok = (size_t)(b * Sc + n * Wc);
  const float4* xg = reinterpret_cast<const float4*>(x + winTok * Dc);

#pragma unroll
  for (int i = 0; i < 12; ++i) {
    const int idx = tid + 256 * i;
    const int r = idx / NQc;
    const int c = idx - r * NQc;
    xs4[r * PQ + c] = xg[idx];
  }
  __syncthreads();

  const int arow = lane & 15;
  const int kg = lane >> 4;
  const int col = 16 * wq + arow;
  f32x4 cacc = {0.f, 0.f, 0.f, 0.f};

  for (int s = 0; s < 24; ++s) {
    const float4 a0 = xs4[arow * PQ + s * 8 + kg * 2];
    const float4 a1 = xs4[arow * PQ + s * 8 + kg * 2 + 1];
    bf16x8 af;
    af[0] = f2bf(a0.x); af[1] = f2bf(a0.y); af[2] = f2bf(a0.z); af[3] = f2bf(a0.w);
    af[4] = f2bf(a1.x); af[5] = f2bf(a1.y); af[6] = f2bf(a1.z); af[7] = f2bf(a1.w);
    const int kbase = s * 32 + kg * 8;
    bf16x8 bf;
#pragma unroll
    for (int j = 0; j < 8; ++j) bf[j] = f2bf(Wg[(size_t)(kbase + j) * Gc + col]);
    cacc = __builtin_amdgcn_mfma_f32_16x16x32_bf16(af, bf, cacc, 0, 0, 0);
  }

#pragma unroll
  for (int r = 0; r < 4; ++r) gl[kg * 4 + r][col] = cacc[r];
  __syncthreads();

  float red[Wc + Ec];
  {
    float g[Wc];
#pragma unroll
    for (int w = 0; w < Wc; ++w) g[w] = gl[w][lane];
#pragma unroll
    for (int w = 0; w < Wc; ++w) red[w] = g[w] * g[w];
#pragma unroll
    for (int e = 0; e < Ec; ++e) red[Wc + e] = g[e] * g[e + 1];
  }
#pragma unroll
  for (int m = 1; m < 64; m <<= 1) {
#pragma unroll
    for (int i = 0; i < Wc + Ec; ++i) red[i] += __shfl_xor(red[i], m, 64);
  }

  float nr[Wc];
#pragma unroll
  for (int w = 0; w < Wc; ++w) nr[w] = sqrtf(red[w]);

  float sv[Ec];
#pragma unroll
  for (int e = 0; e < Ec; ++e)
    sv[e] = red[Wc + e] / (fmaxf(nr[e], 1e-12f) * fmaxf(nr[e + 1], 1e-12f));

  unsigned sel = 0, used = 0;
#pragma unroll
  for (int round = 0; round < Rc; ++round) {
    float best = -1e30f;
    int bi = 0;
#pragma unroll
    for (int e = 0; e < Ec; ++e) {
      const bool ok = ((used >> e) & 3u) == 0u;
      const float v = ok ? sv[e] : -1e30f;
      if (v > best) { best = v; bi = e; }   // strict > => smallest index wins ties
    }
    sel |= (1u << bi);
    used |= (3u << bi);
  }

#pragma unroll
  for (int j3 = 0; j3 < 3; ++j3) {
    const int k = wq * 3 + j3;
    int w = 0, c = 0;
#pragma unroll
    for (int t = 0; t < Wc; ++t) {
      const bool kept = (t == 0) || (((sel >> (t - 1)) & 1u) == 0u);
      if (kept && c == k) w = t;
      c += kept ? 1 : 0;
    }
    const bool mg = (w < Ec) && (((sel >> w) & 1u) != 0u);
    float wi = 0.f, wj = 0.f;
#pragma unroll
    for (int t = 0; t < Wc; ++t) {
      wi = (t == w) ? nr[t] : wi;
      wj = (t == (w + 1)) ? nr[t] : wj;
    }
    float aS = 1.f, bS = 0.f;
    if (mg) {
      const float tot = wi + wj + 1e-8f;
      aS = wi / tot;
      bS = wj / tot;
    }
    const float4* r1 = &xs4[w * PQ];
    const float4* r2 = &xs4[(mg ? (w + 1) : w) * PQ];
    vf4* o = reinterpret_cast<vf4*>(out + (size_t)(wid * KEEPc + k) * Dc);
#pragma unroll
    for (int it = 0; it < 3; ++it) {
      const int i = lane + 64 * it;
      const float4 a = r1[i];
      const float4 bb = r2[i];
      vf4 rr;
      rr.x = fmaf(aS, a.x, bS * bb.x);
      rr.y = fmaf(aS, a.y, bS * bb.y);
      rr.z = fmaf(aS, a.z, bS * bb.z);
      rr.w = fmaf(aS, a.w, bS * bb.w);
      __builtin_nontemporal_store(rr, o + i);
    }
  }

  if (wq == 0 && lane < KEEPc) {
    const int k = lane;
    int w = 0, c = 0;
#pragma unroll
    for (int t = 0; t < Wc; ++t) {
      const bool kept = (t == 0) || (((sel >> (t - 1)) & 1u) == 0u);
      if (kept && c == k) w = t;
      c += kept ? 1 : 0;
    }
    const bool mg = (w < Ec) && (((sel >> w) & 1u) != 0u);
    const int row = wid * KEEPc + k;
    meta[row] = w | (mg ? 16 : 0);
    out[X_ELEMS + S_ELEMS + (size_t)row] = (float)pos[winTok + w];
  }
}

// ---- K2: one 256-thread block per s-row; 4 independent f4 per thread ----
// Single A/B variable vs round 10: PLAIN stores instead of nontemporal
// (the 6.9 TB/s fill kernel uses plain stores; NT may de-optimize DRAM bursts).
__global__ __launch_bounds__(256)
void tm_srows(const float* __restrict__ src, const int* __restrict__ meta,
              float* __restrict__ outs) {
  const int gid = blockIdx.x;              // 0..12287
  const int t = threadIdx.x;

  const int mt = meta[gid];                // block-uniform, L2-hot
  const int w = mt & 15;
  const bool mg = (mt & 16) != 0;

  const int b = gid / (NWc * KEEPc);
  const int m = gid - b * (NWc * KEEPc);
  const int n = m / KEEPc;

  const vf4* s1 = reinterpret_cast<const vf4*>(src + (size_t)(b * Sc + n * Wc + w) * Sc);
  vf4* o = reinterpret_cast<vf4*>(outs + (size_t)gid * Sc);

  if (mg) {
    const vf4* s2 = s1 + (Sc / 4);
    vf4 a0 = s1[t];
    vf4 a1 = s1[t + 256];
    vf4 a2 = s1[t + 512];
    vf4 a3 = s1[t + 768];
    const vf4 c0 = s2[t];
    const vf4 c1 = s2[t + 256];
    const vf4 c2 = s2[t + 512];
    const vf4 c3 = s2[t + 768];
    o[t] = a0 + c0;
    o[t + 256] = a1 + c1;
    o[t + 512] = a2 + c2;
    o[t + 768] = a3 + c3;
  } else {
    const vf4 a0 = s1[t];
    const vf4 a1 = s1[t + 256];
    const vf4 a2 = s1[t + 512];
    const vf4 a3 = s1[t + 768];
    o[t] = a0;
    o[t + 256] = a1;
    o[t + 512] = a2;
    o[t + 768] = a3;
  }
}

extern "C" void kernel_launch(void* const* d_in, const int* in_sizes, int n_in,
                              void* d_out, int out_size, void* d_ws, size_t ws_size,
                              hipStream_t stream) {
  const float* x = (const float*)d_in[0];
  const float* src = (const float*)d_in[1];
  const int* pos = (const int*)d_in[2];
  const float* Wg = (const float*)d_in[3];
  float* out = (float*)d_out;
  int* meta = (int*)d_ws;

  tm_select<<<dim3(Bc * NWc), dim3(256), 0, stream>>>(x, pos, Wg, out, meta);
  tm_srows<<<dim3(NROWS), dim3(256), 0, stream>>>(src, meta, out + X_ELEMS);
}

// Round 13
// 122.336 us; speedup vs baseline: 1.0857x; 1.0794x over previous
//
#include <hip/hip_runtime.h>
#include <math.h>

namespace {
constexpr int Bc = 4, Sc = 4096, Dc = 768, Gc = 64, Wc = 16, Rc = 4;
constexpr int NWc = Sc / Wc;          // 256 windows per batch row
constexpr int KEEPc = Wc - Rc;        // 12 kept tokens per window
constexpr int Ec = Wc - 1;            // 15 adjacent edges
constexpr int NQc = Dc / 4;           // 192 float4 per x row
constexpr int PQ = NQc + 1;           // padded LDS row stride (f4)
constexpr size_t X_ELEMS = (size_t)Bc * NWc * KEEPc * Dc;
constexpr size_t S_ELEMS = (size_t)Bc * NWc * KEEPc * Sc;
constexpr int NROWS = Bc * NWc * KEEPc;                    // 12288 output rows
constexpr int RPB = 6;                                     // rows per K2 block

typedef float vf4 __attribute__((ext_vector_type(4)));
typedef float f32x4 __attribute__((ext_vector_type(4)));
typedef short bf16x8 __attribute__((ext_vector_type(8)));

__device__ inline short f2bf(float f) {      // native HW cvt, compiler packs pairs
  return __builtin_bit_cast(short, (__bf16)f);
}
}

// ---- K1: MFMA gating GEMM + greedy selection + x_out + p_out + meta ----
// (round-9 winner, unchanged: ~15-18 us, near its 88 MB memory floor)
__global__ __launch_bounds__(256)
void tm_select(const float* __restrict__ x, const int* __restrict__ pos,
               const float* __restrict__ Wg, float* __restrict__ out,
               int* __restrict__ meta) {
  const int wid = blockIdx.x;          // 0..1023
  const int b = wid >> 8;
  const int n = wid & (NWc - 1);
  const int tid = threadIdx.x;
  const int lane = tid & 63;
  const int wq = tid >> 6;

  __shared__ float4 xs4[Wc * PQ];      // ~49 KB, padded rows
  __shared__ float gl[Wc][Gc];         // 4 KB: g = x @ Wg

  const size_t winTok = (size_t)(b * Sc + n * Wc);
  const float4* xg = reinterpret_cast<const float4*>(x + winTok * Dc);

#pragma unroll
  for (int i = 0; i < 12; ++i) {
    const int idx = tid + 256 * i;
    const int r = idx / NQc;
    const int c = idx - r * NQc;
    xs4[r * PQ + c] = xg[idx];
  }
  __syncthreads();

  const int arow = lane & 15;
  const int kg = lane >> 4;
  const int col = 16 * wq + arow;
  f32x4 cacc = {0.f, 0.f, 0.f, 0.f};

  for (int s = 0; s < 24; ++s) {
    const float4 a0 = xs4[arow * PQ + s * 8 + kg * 2];
    const float4 a1 = xs4[arow * PQ + s * 8 + kg * 2 + 1];
    bf16x8 af;
    af[0] = f2bf(a0.x); af[1] = f2bf(a0.y); af[2] = f2bf(a0.z); af[3] = f2bf(a0.w);
    af[4] = f2bf(a1.x); af[5] = f2bf(a1.y); af[6] = f2bf(a1.z); af[7] = f2bf(a1.w);
    const int kbase = s * 32 + kg * 8;
    bf16x8 bf;
#pragma unroll
    for (int j = 0; j < 8; ++j) bf[j] = f2bf(Wg[(size_t)(kbase + j) * Gc + col]);
    cacc = __builtin_amdgcn_mfma_f32_16x16x32_bf16(af, bf, cacc, 0, 0, 0);
  }

#pragma unroll
  for (int r = 0; r < 4; ++r) gl[kg * 4 + r][col] = cacc[r];
  __syncthreads();

  float red[Wc + Ec];
  {
    float g[Wc];
#pragma unroll
    for (int w = 0; w < Wc; ++w) g[w] = gl[w][lane];
#pragma unroll
    for (int w = 0; w < Wc; ++w) red[w] = g[w] * g[w];
#pragma unroll
    for (int e = 0; e < Ec; ++e) red[Wc + e] = g[e] * g[e + 1];
  }
#pragma unroll
  for (int m = 1; m < 64; m <<= 1) {
#pragma unroll
    for (int i = 0; i < Wc + Ec; ++i) red[i] += __shfl_xor(red[i], m, 64);
  }

  float nr[Wc];
#pragma unroll
  for (int w = 0; w < Wc; ++w) nr[w] = sqrtf(red[w]);

  float sv[Ec];
#pragma unroll
  for (int e = 0; e < Ec; ++e)
    sv[e] = red[Wc + e] / (fmaxf(nr[e], 1e-12f) * fmaxf(nr[e + 1], 1e-12f));

  unsigned sel = 0, used = 0;
#pragma unroll
  for (int round = 0; round < Rc; ++round) {
    float best = -1e30f;
    int bi = 0;
#pragma unroll
    for (int e = 0; e < Ec; ++e) {
      const bool ok = ((used >> e) & 3u) == 0u;
      const float v = ok ? sv[e] : -1e30f;
      if (v > best) { best = v; bi = e; }   // strict > => smallest index wins ties
    }
    sel |= (1u << bi);
    used |= (3u << bi);
  }

#pragma unroll
  for (int j3 = 0; j3 < 3; ++j3) {
    const int k = wq * 3 + j3;
    int w = 0, c = 0;
#pragma unroll
    for (int t = 0; t < Wc; ++t) {
      const bool kept = (t == 0) || (((sel >> (t - 1)) & 1u) == 0u);
      if (kept && c == k) w = t;
      c += kept ? 1 : 0;
    }
    const bool mg = (w < Ec) && (((sel >> w) & 1u) != 0u);
    float wi = 0.f, wj = 0.f;
#pragma unroll
    for (int t = 0; t < Wc; ++t) {
      wi = (t == w) ? nr[t] : wi;
      wj = (t == (w + 1)) ? nr[t] : wj;
    }
    float aS = 1.f, bS = 0.f;
    if (mg) {
      const float tot = wi + wj + 1e-8f;
      aS = wi / tot;
      bS = wj / tot;
    }
    const float4* r1 = &xs4[w * PQ];
    const float4* r2 = &xs4[(mg ? (w + 1) : w) * PQ];
    vf4* o = reinterpret_cast<vf4*>(out + (size_t)(wid * KEEPc + k) * Dc);
#pragma unroll
    for (int it = 0; it < 3; ++it) {
      const int i = lane + 64 * it;
      const float4 a = r1[i];
      const float4 bb = r2[i];
      vf4 rr;
      rr.x = fmaf(aS, a.x, bS * bb.x);
      rr.y = fmaf(aS, a.y, bS * bb.y);
      rr.z = fmaf(aS, a.z, bS * bb.z);
      rr.w = fmaf(aS, a.w, bS * bb.w);
      __builtin_nontemporal_store(rr, o + i);
    }
  }

  if (wq == 0 && lane < KEEPc) {
    const int k = lane;
    int w = 0, c = 0;
#pragma unroll
    for (int t = 0; t < Wc; ++t) {
      const bool kept = (t == 0) || (((sel >> (t - 1)) & 1u) == 0u);
      if (kept && c == k) w = t;
      c += kept ? 1 : 0;
    }
    const bool mg = (w < Ec) && (((sel >> w) & 1u) != 0u);
    const int row = wid * KEEPc + k;
    meta[row] = w | (mg ? 16 : 0);
    out[X_ELEMS + S_ELEMS + (size_t)row] = (float)pos[winTok + w];
  }
}

// ---- K2: persistent grid-stride blocks: 2048 blocks x 256 thr, 6 rows each.
// NT stores (round-12 A/B: NT beats plain by ~13 us). Full unroll lets the
// compiler hoist next-row loads over current-row stores (cross-iter ILP).
__global__ __launch_bounds__(256)
void tm_srows(const float* __restrict__ src, const int* __restrict__ meta,
              float* __restrict__ outs) {
  const int base = blockIdx.x * RPB;       // consecutive rows -> 96 KB stream
  const int t = threadIdx.x;

#pragma unroll
  for (int i = 0; i < RPB; ++i) {
    const int gid = base + i;
    const int mt = meta[gid];              // block-uniform, L2-hot
    const int w = mt & 15;
    const bool mg = (mt & 16) != 0;

    const int b = gid / (NWc * KEEPc);
    const int m = gid - b * (NWc * KEEPc);
    const int n = m / KEEPc;

    const vf4* s1 =
        reinterpret_cast<const vf4*>(src + (size_t)(b * Sc + n * Wc + w) * Sc);
    vf4* o = reinterpret_cast<vf4*>(outs + (size_t)gid * Sc);

    vf4 a0 = s1[t];
    vf4 a1 = s1[t + 256];
    vf4 a2 = s1[t + 512];
    vf4 a3 = s1[t + 768];
    if (mg) {
      const vf4* s2 = s1 + (Sc / 4);
      a0 = a0 + s2[t];
      a1 = a1 + s2[t + 256];
      a2 = a2 + s2[t + 512];
      a3 = a3 + s2[t + 768];
    }
    __builtin_nontemporal_store(a0, o + t);
    __builtin_nontemporal_store(a1, o + t + 256);
    __builtin_nontemporal_store(a2, o + t + 512);
    __builtin_nontemporal_store(a3, o + t + 768);
  }
}

extern "C" void kernel_launch(void* const* d_in, const int* in_sizes, int n_in,
                              void* d_out, int out_size, void* d_ws, size_t ws_size,
                              hipStream_t stream) {
  const float* x = (const float*)d_in[0];
  const float* src = (const float*)d_in[1];
  const int* pos = (const int*)d_in[2];
  const float* Wg = (const float*)d_in[3];
  float* out = (float*)d_out;
  int* meta = (int*)d_ws;

  tm_select<<<dim3(Bc * NWc), dim3(256), 0, stream>>>(x, pos, Wg, out, meta);
  tm_srows<<<dim3(NROWS / RPB), dim3(256), 0, stream>>>(src, meta, out + X_ELEMS);
}

// Round 14
// 104.367 us; speedup vs baseline: 1.2726x; 1.1722x over previous
//
#include <hip/hip_runtime.h>
#include <math.h>

namespace {
constexpr int Bc = 4, Sc = 4096, Dc = 768, Gc = 64, Wc = 16, Rc = 4;
constexpr int NWc = Sc / Wc;          // 256 windows per batch row
constexpr int KEEPc = Wc - Rc;        // 12 kept tokens per window
constexpr int Ec = Wc - 1;            // 15 adjacent edges
constexpr int NQc = Dc / 4;           // 192 float4 per x row
constexpr int PQ = NQc + 1;           // padded LDS row stride (f4)
constexpr size_t X_ELEMS = (size_t)Bc * NWc * KEEPc * Dc;
constexpr size_t S_ELEMS = (size_t)Bc * NWc * KEEPc * Sc;
constexpr int NROWS = Bc * NWc * KEEPc;                    // 12288 output rows

typedef float vf4 __attribute__((ext_vector_type(4)));
typedef float f32x4 __attribute__((ext_vector_type(4)));
typedef short bf16x8 __attribute__((ext_vector_type(8)));

__device__ inline short f2bf(float f) {      // native HW cvt, compiler packs pairs
  return __builtin_bit_cast(short, (__bf16)f);
}
}

// ---- K1: MFMA gating GEMM + greedy selection + x_out + p_out + meta ----
// Round-9 winner + ONE change: x staging loads are NONTEMPORAL (x is read
// exactly once, by this kernel — don't let it evict source from L3).
__global__ __launch_bounds__(256)
void tm_select(const float* __restrict__ x, const int* __restrict__ pos,
               const float* __restrict__ Wg, float* __restrict__ out,
               int* __restrict__ meta) {
  const int wid = blockIdx.x;          // 0..1023
  const int b = wid >> 8;
  const int n = wid & (NWc - 1);
  const int tid = threadIdx.x;
  const int lane = tid & 63;
  const int wq = tid >> 6;

  __shared__ float4 xs4[Wc * PQ];      // ~49 KB, padded rows
  __shared__ float gl[Wc][Gc];         // 4 KB: g = x @ Wg

  const size_t winTok = (size_t)(b * Sc + n * Wc);
  const vf4* xg = reinterpret_cast<const vf4*>(x + winTok * Dc);

#pragma unroll
  for (int i = 0; i < 12; ++i) {
    const int idx = tid + 256 * i;
    const int r = idx / NQc;
    const int c = idx - r * NQc;
    xs4[r * PQ + c] = __builtin_bit_cast(float4, __builtin_nontemporal_load(xg + idx));
  }
  __syncthreads();

  const int arow = lane & 15;
  const int kg = lane >> 4;
  const int col = 16 * wq + arow;
  f32x4 cacc = {0.f, 0.f, 0.f, 0.f};

  for (int s = 0; s < 24; ++s) {
    const float4 a0 = xs4[arow * PQ + s * 8 + kg * 2];
    const float4 a1 = xs4[arow * PQ + s * 8 + kg * 2 + 1];
    bf16x8 af;
    af[0] = f2bf(a0.x); af[1] = f2bf(a0.y); af[2] = f2bf(a0.z); af[3] = f2bf(a0.w);
    af[4] = f2bf(a1.x); af[5] = f2bf(a1.y); af[6] = f2bf(a1.z); af[7] = f2bf(a1.w);
    const int kbase = s * 32 + kg * 8;
    bf16x8 bf;
#pragma unroll
    for (int j = 0; j < 8; ++j) bf[j] = f2bf(Wg[(size_t)(kbase + j) * Gc + col]);
    cacc = __builtin_amdgcn_mfma_f32_16x16x32_bf16(af, bf, cacc, 0, 0, 0);
  }

#pragma unroll
  for (int r = 0; r < 4; ++r) gl[kg * 4 + r][col] = cacc[r];
  __syncthreads();

  float red[Wc + Ec];
  {
    float g[Wc];
#pragma unroll
    for (int w = 0; w < Wc; ++w) g[w] = gl[w][lane];
#pragma unroll
    for (int w = 0; w < Wc; ++w) red[w] = g[w] * g[w];
#pragma unroll
    for (int e = 0; e < Ec; ++e) red[Wc + e] = g[e] * g[e + 1];
  }
#pragma unroll
  for (int m = 1; m < 64; m <<= 1) {
#pragma unroll
    for (int i = 0; i < Wc + Ec; ++i) red[i] += __shfl_xor(red[i], m, 64);
  }

  float nr[Wc];
#pragma unroll
  for (int w = 0; w < Wc; ++w) nr[w] = sqrtf(red[w]);

  float sv[Ec];
#pragma unroll
  for (int e = 0; e < Ec; ++e)
    sv[e] = red[Wc + e] / (fmaxf(nr[e], 1e-12f) * fmaxf(nr[e + 1], 1e-12f));

  unsigned sel = 0, used = 0;
#pragma unroll
  for (int round = 0; round < Rc; ++round) {
    float best = -1e30f;
    int bi = 0;
#pragma unroll
    for (int e = 0; e < Ec; ++e) {
      const bool ok = ((used >> e) & 3u) == 0u;
      const float v = ok ? sv[e] : -1e30f;
      if (v > best) { best = v; bi = e; }   // strict > => smallest index wins ties
    }
    sel |= (1u << bi);
    used |= (3u << bi);
  }

#pragma unroll
  for (int j3 = 0; j3 < 3; ++j3) {
    const int k = wq * 3 + j3;
    int w = 0, c = 0;
#pragma unroll
    for (int t = 0; t < Wc; ++t) {
      const bool kept = (t == 0) || (((sel >> (t - 1)) & 1u) == 0u);
      if (kept && c == k) w = t;
      c += kept ? 1 : 0;
    }
    const bool mg = (w < Ec) && (((sel >> w) & 1u) != 0u);
    float wi = 0.f, wj = 0.f;
#pragma unroll
    for (int t = 0; t < Wc; ++t) {
      wi = (t == w) ? nr[t] : wi;
      wj = (t == (w + 1)) ? nr[t] : wj;
    }
    float aS = 1.f, bS = 0.f;
    if (mg) {
      const float tot = wi + wj + 1e-8f;
      aS = wi / tot;
      bS = wj / tot;
    }
    const float4* r1 = &xs4[w * PQ];
    const float4* r2 = &xs4[(mg ? (w + 1) : w) * PQ];
    vf4* o = reinterpret_cast<vf4*>(out + (size_t)(wid * KEEPc + k) * Dc);
#pragma unroll
    for (int it = 0; it < 3; ++it) {
      const int i = lane + 64 * it;
      const float4 a = r1[i];
      const float4 bb = r2[i];
      vf4 rr;
      rr.x = fmaf(aS, a.x, bS * bb.x);
      rr.y = fmaf(aS, a.y, bS * bb.y);
      rr.z = fmaf(aS, a.z, bS * bb.z);
      rr.w = fmaf(aS, a.w, bS * bb.w);
      __builtin_nontemporal_store(rr, o + i);
    }
  }

  if (wq == 0 && lane < KEEPc) {
    const int k = lane;
    int w = 0, c = 0;
#pragma unroll
    for (int t = 0; t < Wc; ++t) {
      const bool kept = (t == 0) || (((sel >> (t - 1)) & 1u) == 0u);
      if (kept && c == k) w = t;
      c += kept ? 1 : 0;
    }
    const bool mg = (w < Ec) && (((sel >> w) & 1u) != 0u);
    const int row = wid * KEEPc + k;
    meta[row] = w | (mg ? 16 : 0);
    out[X_ELEMS + S_ELEMS + (size_t)row] = (float)pos[winTok + w];
  }
}

// ---- K2: round-9 winner verbatim: one 1024-thread block per s-row,
// 1 f4/thread, plain loads (L3 replay hits) + NT stores (no pollution). ----
__global__ __launch_bounds__(1024)
void tm_srows(const float* __restrict__ src, const int* __restrict__ meta,
              float* __restrict__ outs) {
  const int gid = blockIdx.x;              // 0..12287
  const int t = threadIdx.x;

  const int mt = meta[gid];                // block-uniform
  const int w = mt & 15;
  const bool mg = (mt & 16) != 0;

  const int b = gid / (NWc * KEEPc);
  const int m = gid - b * (NWc * KEEPc);
  const int n = m / KEEPc;

  const vf4* s1 = reinterpret_cast<const vf4*>(src + (size_t)(b * Sc + n * Wc + w) * Sc);
  vf4 a = s1[t];
  if (mg) a = a + s1[t + (Sc / 4)];
  __builtin_nontemporal_store(a, reinterpret_cast<vf4*>(outs + (size_t)gid * Sc) + t);
}

extern "C" void kernel_launch(void* const* d_in, const int* in_sizes, int n_in,
                              void* d_out, int out_size, void* d_ws, size_t ws_size,
                              hipStream_t stream) {
  const float* x = (const float*)d_in[0];
  const float* src = (const float*)d_in[1];
  const int* pos = (const int*)d_in[2];
  const float* Wg = (const float*)d_in[3];
  float* out = (float*)d_out;
  int* meta = (int*)d_ws;

  tm_select<<<dim3(Bc * NWc), dim3(256), 0, stream>>>(x, pos, Wg, out, meta);
  tm_srows<<<dim3(NROWS), dim3(1024), 0, stream>>>(src, meta, out + X_ELEMS);
}